// Round 9
// baseline (324.598 us; speedup 1.0000x reference)
//
#include <hip/hip_runtime.h>
#include <hip/hip_bf16.h>

// Head: x(8,2048,1024) fp32 @ {Wq,Wk,Wv}(1024,128) fp32
//   -> causal softmax((QK^T)/32) @ V -> out FP32.
// R8 counters: qkv 85us @ occupancy==grid cap, all pipes idle -> latency-bound
// (loads consumed by the same iteration that issues them). R9:
//   qkv: cross-iteration register double-buffer of x loads + grid 1024.
//   attn: split-K at 512 (max 16 tiles/chunk, grid 2560) with exact-additive
//         merge (static-max softmax); runtime ws_size gate -> fallback 1024.

typedef __attribute__((ext_vector_type(8))) short bf16x8;   // 8 bf16 = 4 VGPRs
typedef __attribute__((ext_vector_type(4))) float f32x4;    // MFMA C/D frag

#define NB   8
#define TT   2048
#define CDIM 1024
#define HD   128
#define NTOK (NB * TT)   // 16384
#define NW   384

using bf16 = __hip_bfloat16;

__device__ __forceinline__ short f2bs(float f) {          // RNE bf16
    unsigned u = __builtin_bit_cast(unsigned, f);
    return (short)((u + 0x7FFF + ((u >> 16) & 1)) >> 16);
}

// ---------- prep: Wt[w*128+h][c] = bf16(W_w[c][h]), coalesced via LDS ----------
__global__ __launch_bounds__(256) void prep_w_kernel(
        const float* __restrict__ Wq, const float* __restrict__ Wk,
        const float* __restrict__ Wv, bf16* __restrict__ Wt) {
    __shared__ float tile[32][129];
    const int tid = threadIdx.x;
    const int w = blockIdx.x >> 5, c0 = (blockIdx.x & 31) * 32;
    const float* W = (w == 0) ? Wq : (w == 1) ? Wk : Wv;

    const int rr = tid >> 3, hc = (tid & 7) * 16;
    const float4* src = (const float4*)(W + (long)(c0 + rr) * HD + hc);
    #pragma unroll
    for (int j = 0; j < 4; j++) {
        float4 v = src[j];
        tile[rr][hc + j*4 + 0] = v.x; tile[rr][hc + j*4 + 1] = v.y;
        tile[rr][hc + j*4 + 2] = v.z; tile[rr][hc + j*4 + 3] = v.w;
    }
    __syncthreads();

    const int c = tid & 31, hb = tid >> 5;
    #pragma unroll
    for (int hp = 0; hp < 16; hp++) {
        int h = hp * 8 + hb;
        Wt[(long)(w * HD + h) * CDIM + c0 + c] = __float2bfloat16(tile[c][h]);
    }
}

// ---------- QKV projection: (16384x1024)@(1024x384) bf16 MFMA ----------
// grid 1024 (16 rows), block 256 = 4 waves; wave w: cols [96w,96w+96).
// x loads double-buffered ACROSS 128-k iterations: kb+1's 8 float4 issued
// before kb's compute -> latency hidden by ~500cyc compute x 3 waves/SIMD.
#define LOADX(BUF, KB)                                                   \
    _Pragma("unroll")                                                    \
    for (int j = 0; j < 4; j++) {                                        \
        xa[BUF][2*j]     = arow[32*(KB) + 8*j];                          \
        xa[BUF][2*j + 1] = arow[32*(KB) + 8*j + 1];                      \
    }

__global__ __launch_bounds__(256) void qkv_proj_kernel(
        const float* __restrict__ x, const bf16* __restrict__ Wt,
        bf16* __restrict__ Q, bf16* __restrict__ K, bf16* __restrict__ Vt) {
    const int tid  = threadIdx.x;
    const int wave = tid >> 6, lane = tid & 63;
    const int quad = lane >> 4, ln = lane & 15;
    const long mbase = (long)blockIdx.x * 16;
    const int  n0 = wave * 96;

    const f32x4 zero = {0.f, 0.f, 0.f, 0.f};
    f32x4 acc[6];
    #pragma unroll
    for (int nt = 0; nt < 6; nt++) acc[nt] = zero;

    const float4* arow = (const float4*)(x + (mbase + ln) * CDIM) + quad * 2;
    const bf16* brow[6];
    #pragma unroll
    for (int nt = 0; nt < 6; nt++)
        brow[nt] = Wt + (long)(n0 + nt*16 + ln) * CDIM + quad * 8;

    float4 xa[2][8];
    LOADX(0, 0)
    for (int kb = 0; kb < 8; kb++) {
        const int cur = kb & 1;
        if (kb + 1 < 8) { LOADX(cur ^ 1, kb + 1) }     // prefetch next block
        #pragma unroll
        for (int s = 0; s < 4; s++) {
            float4 u = xa[cur][2*s], v = xa[cur][2*s + 1];
            bf16x8 af;
            af[0] = f2bs(u.x); af[1] = f2bs(u.y);
            af[2] = f2bs(u.z); af[3] = f2bs(u.w);
            af[4] = f2bs(v.x); af[5] = f2bs(v.y);
            af[6] = f2bs(v.z); af[7] = f2bs(v.w);
            #pragma unroll
            for (int nt = 0; nt < 6; nt++) {
                bf16x8 bfv = *(const bf16x8*)(brow[nt] + kb*128 + s*32);
                acc[nt] = __builtin_amdgcn_mfma_f32_16x16x32_bf16(af, bfv, acc[nt], 0, 0, 0);
            }
        }
    }

    // C/D: col = ln, row = quad*4 + r
    #pragma unroll
    for (int nt = 0; nt < 6; nt++) {
        const int n = n0 + nt*16 + ln;
        #pragma unroll
        for (int r = 0; r < 4; r++) {
            long g = mbase + quad*4 + r;
            int b = (int)(g >> 11), t = (int)(g & (TT - 1));
            bf16 hv = __float2bfloat16(acc[nt][r]);
            if (n < 128)      Q [((long)b*TT + t)*HD + n]         = hv;
            else if (n < 256) K [((long)b*TT + t)*HD + (n - 128)] = hv;
            else              Vt[((long)b*HD + (n - 256))*TT + t] = hv;
        }
    }
}

// ---------- causal flash attention, static-max softmax, split-K ----------
// mode=1 (deep): chunks of 512 keys; per b: 32 single-chunk q-tiles (qi<32)
//   + 288 partial chunks (qi 32..127, nchunks=qi/32+1). grid 8x320.
// mode=0 (shallow fallback): R8 mapping, split at 1024. grid 8x192.
__device__ __forceinline__ void load_ktile(const bf16* Kb, int j0, int ln,
                                           int quad, bf16x8 kf[4][2]) {
    #pragma unroll
    for (int kc = 0; kc < 4; kc++)
        #pragma unroll
        for (int nt = 0; nt < 2; nt++)
            kf[kc][nt] = *(const bf16x8*)(Kb + (long)(j0 + nt*16 + ln)*HD + kc*32 + quad*8);
}

#define ATTN_TILE(CUR, NXT)                                                      \
  {                                                                              \
    const int j0 = klo + kt * 32;                                                \
    bf16x8 vf[8];                                                                \
    _Pragma("unroll")                                                            \
    for (int ht = 0; ht < 8; ht++)                                               \
        vf[ht] = *(const bf16x8*)(Vb + (long)(ht*16 + ln)*TT + j0 + quad*8);     \
    if (kt + 1 < ntiles) load_ktile(Kb, j0 + 32, ln, quad, NXT);                 \
    f32x4 s[2]; s[0] = zero; s[1] = zero;                                        \
    _Pragma("unroll")                                                            \
    for (int kc = 0; kc < 4; kc++) {                                             \
        s[0] = __builtin_amdgcn_mfma_f32_16x16x32_bf16(qf[kc], CUR[kc][0], s[0], 0, 0, 0); \
        s[1] = __builtin_amdgcn_mfma_f32_16x16x32_bf16(qf[kc], CUR[kc][1], s[1], 0, 0, 0); \
    }                                                                            \
    short* pb = pbuf[kt & 1];                                                    \
    _Pragma("unroll")                                                            \
    for (int r = 0; r < 4; r++) {                                                \
        const int q = qb + quad*4 + r;                                           \
        _Pragma("unroll")                                                        \
        for (int nt = 0; nt < 2; nt++) {                                         \
            float p = __expf(s[nt][r] * 0.03125f);                               \
            if (j0 + nt*16 + ln > q) p = 0.f;                                    \
            li[r] += p;                                                          \
            pb[(quad*4 + r)*40 + nt*16 + ln] = f2bs(p);                          \
        }                                                                        \
    }                                                                            \
    bf16x8 pf = *(const bf16x8*)&pb[ln*40 + quad*8];                             \
    _Pragma("unroll")                                                            \
    for (int ht = 0; ht < 8; ht++)                                               \
        o[ht] = __builtin_amdgcn_mfma_f32_16x16x32_bf16(pf, vf[ht], o[ht], 0, 0, 0); \
    kt++;                                                                        \
  }

__global__ __launch_bounds__(64) void attn_kernel(
        const bf16* __restrict__ Q, const bf16* __restrict__ K,
        const bf16* __restrict__ Vt, float* __restrict__ out,
        float* __restrict__ po, float* __restrict__ pl, int mode) {
    __shared__ __align__(16) short pbuf[2][16 * 40];

    const int lane = threadIdx.x;
    const int quad = lane >> 4, ln = lane & 15;
    const int b   = blockIdx.x & 7;
    const int cid = blockIdx.x >> 3;

    int qi, klo, khi, slot; bool fin;
    if (mode) {
        if (cid < 288) {
            int c;
            if (cid < 64)       { qi = 32 + (cid >> 1);  c = cid & 1; }
            else if (cid < 160) { int t = cid - 64;  qi = 64 + t / 3;  c = t - (qi - 64) * 3; }
            else                { int t = cid - 160; qi = 96 + (t >> 2); c = t & 3; }
            klo = c * 512; khi = min(klo + 512, qi*16 + 16); fin = false;
            slot = b * 288 + cid;
        } else { qi = cid - 288; klo = 0; khi = qi*16 + 16; fin = true; slot = 0; }
    } else {
        if (cid < 64)       { qi = 127 - cid;        klo = 0;    khi = 1024;       fin = false; slot = (b*64 + qi - 64)*2; }
        else if (cid < 128) { qi = 127 - (cid - 64); klo = 1024; khi = qi*16 + 16; fin = false; slot = (b*64 + qi - 64)*2 + 1; }
        else                { qi = 191 - cid;        klo = 0;    khi = qi*16 + 16; fin = true;  slot = 0; }
    }
    const int qb = qi * 16;
    const int ntiles = (khi - klo + 31) >> 5;

    const bf16* Qb = Q  + (long)b * TT * HD;
    const bf16* Kb = K  + (long)b * TT * HD;
    const bf16* Vb = Vt + (long)b * HD * TT;

    bf16x8 qf[4];
    #pragma unroll
    for (int kc = 0; kc < 4; kc++)
        qf[kc] = *(const bf16x8*)(Qb + (long)(qb + ln)*HD + kc*32 + quad*8);

    const f32x4 zero = {0.f, 0.f, 0.f, 0.f};
    f32x4 o[8];
    #pragma unroll
    for (int ht = 0; ht < 8; ht++) o[ht] = zero;
    float li[4] = {0.f, 0.f, 0.f, 0.f};

    bf16x8 kfA[4][2], kfB[4][2];
    load_ktile(Kb, klo, ln, quad, kfA);
    int kt = 0;
    while (kt < ntiles) {
        ATTN_TILE(kfA, kfB)
        if (kt >= ntiles) break;
        ATTN_TILE(kfB, kfA)
    }

    #pragma unroll
    for (int r = 0; r < 4; r++)
        #pragma unroll
        for (int d = 1; d < 16; d <<= 1) li[r] += __shfl_xor(li[r], d);

    if (fin) {
        #pragma unroll
        for (int ht = 0; ht < 8; ht++)
            #pragma unroll
            for (int r = 0; r < 4; r++) {
                const int q = qb + quad*4 + r;
                out[((long)b*TT + q)*HD + ht*16 + ln] = o[ht][r] / li[r];
            }
    } else {
        float* od = po + (long)slot * (16 * HD);
        #pragma unroll
        for (int ht = 0; ht < 8; ht++)
            #pragma unroll
            for (int r = 0; r < 4; r++)
                od[(quad*4 + r)*HD + ht*16 + ln] = o[ht][r];
        if (ln == 0)
            #pragma unroll
            for (int r = 0; r < 4; r++)
                pl[slot*16 + quad*4 + r] = li[r];
    }
}

// ---------- merge partial chunks (exact-additive) ----------
__global__ __launch_bounds__(64) void merge_kernel(
        const float* __restrict__ po, const float* __restrict__ pl,
        float* __restrict__ out, int mode) {
    int b, t, qi, base, nch;
    if (mode) {                                   // grid 8*96, qi 32..127
        b = blockIdx.x / 96; t = blockIdx.x - b * 96; qi = 32 + t;
        nch  = 1 + qi / 32;
        base = b * 288 + ((t < 32) ? 2*t : (t < 64) ? 64 + 3*(t - 32)
                                                    : 160 + 4*(t - 64));
    } else {                                      // grid 8*64, qi 64..127
        b = blockIdx.x >> 6; t = blockIdx.x & 63; qi = 64 + t;
        nch = 2; base = (b*64 + t) * 2;
    }
    const int qb = qi * 16;
    for (int i = threadIdx.x; i < 16 * HD; i += 64) {
        const int row = i >> 7, h = i & 127;
        float osum = 0.f, l = 0.f;
        for (int c = 0; c < nch; c++) {
            osum += po[(long)(base + c) * (16 * HD) + i];
            l    += pl[(base + c) * 16 + row];
        }
        out[((long)b*TT + qb + row)*HD + h] = osum / l;
    }
}

extern "C" void kernel_launch(void* const* d_in, const int* in_sizes, int n_in,
                              void* d_out, int out_size, void* d_ws, size_t ws_size,
                              hipStream_t stream) {
    const float* x  = (const float*)d_in[0];
    const float* Wq = (const float*)d_in[1];
    const float* Wk = (const float*)d_in[2];
    const float* Wv = (const float*)d_in[3];
    float* outp = (float*)d_out;

    bf16* Wt = (bf16*)d_ws;
    bf16* Qm = Wt + (long)NW * CDIM;
    bf16* Km = Qm + (long)NTOK * HD;
    bf16* Vm = Km + (long)NTOK * HD;
    float* po = (float*)(Vm + (long)NTOK * HD);

    // deep (split 512): po 2304 slots (18.9MB) + pl 147KB -> total ~32.4MB
    const size_t base_b = ((size_t)NW*CDIM + 3ul*NTOK*HD) * 2;
    const size_t need_deep = base_b + 2304ul*2048*4 + 2304ul*16*4;
    const int mode = (ws_size >= need_deep) ? 1 : 0;
    const int nslots = mode ? 2304 : 1024;
    float* pl = po + (long)nslots * 2048;

    prep_w_kernel<<<96, 256, 0, stream>>>(Wq, Wk, Wv, Wt);
    qkv_proj_kernel<<<1024, 256, 0, stream>>>(x, Wt, Qm, Km, Vm);
    attn_kernel<<<NB * (mode ? 320 : 192), 64, 0, stream>>>(Qm, Km, Vm, outp, po, pl, mode);
    merge_kernel<<<NB * (mode ? 96 : 64), 64, 0, stream>>>(po, pl, outp, mode);
}